// Round 3
// baseline (95.317 us; speedup 1.0000x reference)
//
#include <hip/hip_runtime.h>
#include <stdint.h>

typedef unsigned long long u64;

#define QS   8192      // rows per quarter-chunk
#define NB   4096      // histogram bins = top 12 bits of mapped x
#define BPT  8         // NB / NTH
#define KOUT 512
#define SLOT 1024      // ws key slots per quarter
#define CBUF 1536      // merge candidate buffer
#define NTH  512

// Monotone float->uint32 map (order-preserving), exactly invertible.
__device__ __forceinline__ uint32_t fmap(float f) {
    uint32_t u = __float_as_uint(f);
    return (u & 0x80000000u) ? ~u : (u | 0x80000000u);
}
__device__ __forceinline__ float funmap(uint32_t m) {
    uint32_t u = (m & 0x80000000u) ? (m & 0x7fffffffu) : ~m;
    return __uint_as_float(u);
}

// Scan per-thread 8-bin group sums (shuffle-based, 3 barriers) and find the
// threshold bin T with cumulative count >= Kb. All NTH threads participate.
__device__ __forceinline__ void find_threshold(uint32_t* hist, uint32_t* wsum,
                                               uint32_t* shT, uint32_t Kb, int tid) {
    uint32_t s = 0;
    const int base = tid * BPT;
    for (int g = 0; g < BPT; ++g) s += hist[base + g];
    const int lane = tid & 63, wid = tid >> 6;
    uint32_t v = s;
    for (int off = 1; off < 64; off <<= 1) {
        uint32_t t = __shfl_up(v, (unsigned)off, 64);
        if (lane >= off) v += t;
    }
    if (lane == 63) wsum[wid] = v;
    __syncthreads();
    if (tid < 8) {
        uint32_t x = wsum[tid];
        for (int off = 1; off < 8; off <<= 1) {
            uint32_t t = __shfl_up(x, (unsigned)off, 8);
            if (tid >= off) x += t;
        }
        wsum[tid] = x;
    }
    __syncthreads();
    const uint32_t woff = (wid > 0) ? wsum[wid - 1] : 0u;
    const uint32_t incl = v + woff;
    const uint32_t excl = incl - s;
    if (Kb > excl && Kb <= incl) {
        uint32_t run = excl;
        int g = 0;
        for (;;) {
            run += hist[base + g];
            if (run >= Kb) break;
            ++g;
        }
        shT[0] = (uint32_t)(base + g);
    }
    __syncthreads();
}

// Kernel 1: per (batch, quarter): select (unsorted) superset of the quarter's
// smallest min(512, validq) keys via bin threshold; write to ws.
__global__ __launch_bounds__(NTH) void quarter_kernel(
    const float* __restrict__ corners, const int* __restrict__ lengths,
    u64* __restrict__ ws_keys, uint32_t* __restrict__ ws_counts,
    int M, int NQ)
{
    const int blk = blockIdx.x;
    const int b = blk / NQ;
    const int q = blk - b * NQ;
    const int tid = threadIdx.x;

    int L = lengths[b];
    if (L < 0) L = 0;
    if (L > M) L = M;
    const int start = q * QS;
    int validq = L - start;
    if (validq < 0) validq = 0;
    if (validq > QS) validq = QS;

    u64* myws = ws_keys + (size_t)blk * SLOT;
    if (validq == 0) { if (tid == 0) ws_counts[blk] = 0; return; }

    const float2* cp = (const float2*)corners + (size_t)b * M + start;

    if (validq <= KOUT) {   // everything is a candidate; no selection needed
        for (int i = tid; i < validq; i += NTH) {
            float2 c = cp[i];
            myws[i] = ((u64)fmap(c.x) << 32) | fmap(c.y);
        }
        if (tid == 0) ws_counts[blk] = (uint32_t)validq;
        return;
    }

    __shared__ uint32_t hist[NB];
    __shared__ uint32_t wsum[8];
    __shared__ uint32_t shT;
    __shared__ uint32_t shcnt;

    for (int i = tid; i < NB; i += NTH) hist[i] = 0u;
    if (tid == 0) { shT = NB - 1; shcnt = 0u; }
    __syncthreads();

    const float4* cp4 = (const float4*)cp;
    const int nv = validq >> 1;
    for (int i = tid; i < nv; i += NTH) {
        float4 v = cp4[i];
        atomicAdd(&hist[fmap(v.x) >> 20], 1u);
        atomicAdd(&hist[fmap(v.z) >> 20], 1u);
    }
    if ((validq & 1) && tid == 0)
        atomicAdd(&hist[fmap(cp[validq - 1].x) >> 20], 1u);
    __syncthreads();

    find_threshold(hist, wsum, &shT, KOUT, tid);
    const uint32_t T = shT;

    for (int i = tid; i < nv; i += NTH) {
        float4 v = cp4[i];
        uint32_t kx = fmap(v.x);
        if ((kx >> 20) <= T) {
            uint32_t p = atomicAdd(&shcnt, 1u);
            if (p < SLOT) myws[p] = ((u64)kx << 32) | fmap(v.y);
        }
        kx = fmap(v.z);
        if ((kx >> 20) <= T) {
            uint32_t p = atomicAdd(&shcnt, 1u);
            if (p < SLOT) myws[p] = ((u64)kx << 32) | fmap(v.w);
        }
    }
    if ((validq & 1) && tid == 0) {
        float2 c = cp[validq - 1];
        uint32_t kx = fmap(c.x);
        if ((kx >> 20) <= T) {
            uint32_t p = atomicAdd(&shcnt, 1u);
            if (p < SLOT) myws[p] = ((u64)kx << 32) | fmap(c.y);
        }
    }
    __syncthreads();
    if (tid == 0) ws_counts[blk] = (shcnt < SLOT) ? shcnt : SLOT;
}

// Kernel 2: per batch: re-threshold the <= NQ*SLOT candidates, rank-select
// the smallest Kb, decode, write sorted + zero-pad.
__global__ __launch_bounds__(NTH) void merge_kernel(
    const int* __restrict__ lengths, const u64* __restrict__ ws_keys,
    const uint32_t* __restrict__ ws_counts, float* __restrict__ out,
    int M, int NQ)
{
    const int b = blockIdx.x;
    const int tid = threadIdx.x;
    int L = lengths[b];
    if (L < 0) L = 0;
    if (L > M) L = M;
    const int Kb = (L < KOUT) ? L : KOUT;
    float2* outb = (float2*)(out + (size_t)b * (2 * KOUT));

    for (int j = Kb + tid; j < KOUT; j += NTH)
        outb[j] = make_float2(0.0f, 0.0f);
    if (Kb == 0) return;

    __shared__ uint32_t hist[NB];
    __shared__ uint32_t wsum[8];
    __shared__ uint32_t shT;
    __shared__ uint32_t shcnt;
    __shared__ u64 cbuf[CBUF];

    for (int i = tid; i < NB; i += NTH) hist[i] = 0u;
    if (tid == 0) { shT = NB - 1; shcnt = 0u; }
    __syncthreads();

    const u64* base = ws_keys + (size_t)b * NQ * SLOT;
    for (int q = 0; q < NQ; ++q) {
        const int nq = (int)ws_counts[b * NQ + q];
        const u64* lst = base + (size_t)q * SLOT;
        for (int i = tid; i < nq; i += NTH)
            atomicAdd(&hist[(uint32_t)(lst[i] >> 52)], 1u);
    }
    __syncthreads();

    find_threshold(hist, wsum, &shT, (uint32_t)Kb, tid);
    const uint32_t T = shT;

    for (int q = 0; q < NQ; ++q) {
        const int nq = (int)ws_counts[b * NQ + q];
        const u64* lst = base + (size_t)q * SLOT;
        for (int i = tid; i < nq; i += NTH) {
            u64 key = lst[i];
            if ((uint32_t)(key >> 52) <= T) {
                uint32_t p = atomicAdd(&shcnt, 1u);
                if (p < CBUF) cbuf[p] = key;
            }
        }
    }
    __syncthreads();
    const int n2 = (int)((shcnt < CBUF) ? shcnt : CBUF);

    for (int i = tid; i < n2; i += NTH) {
        u64 ki = cbuf[i];
        uint32_t r = 0;
        for (int j = 0; j < n2; ++j) {
            u64 kj = cbuf[j];
            r += (kj < ki) || (kj == ki && j < i);
        }
        if (r < (uint32_t)Kb)
            outb[r] = make_float2(funmap((uint32_t)(ki >> 32)), funmap((uint32_t)ki));
    }
}

extern "C" void kernel_launch(void* const* d_in, const int* in_sizes, int n_in,
                              void* d_out, int out_size, void* d_ws, size_t ws_size,
                              hipStream_t stream) {
    const float* corners = (const float*)d_in[0];
    const int* lengths   = (const int*)d_in[1];
    float* out = (float*)d_out;
    const int B = in_sizes[1];
    const int M = in_sizes[0] / (B * 2);
    const int NQ = (M + QS - 1) / QS;   // 4 for M=32768

    u64* ws_keys = (u64*)d_ws;
    uint32_t* ws_counts = (uint32_t*)((char*)d_ws + (size_t)B * NQ * SLOT * sizeof(u64));

    quarter_kernel<<<B * NQ, NTH, 0, stream>>>(corners, lengths, ws_keys, ws_counts, M, NQ);
    merge_kernel<<<B, NTH, 0, stream>>>(lengths, ws_keys, ws_counts, out, M, NQ);
}

// Round 4
// 90.834 us; speedup vs baseline: 1.0494x; 1.0494x over previous
//
#include <hip/hip_runtime.h>
#include <stdint.h>
#include <math.h>

typedef unsigned long long u64;

#define KOUT  512
#define CHUNK 4096     // rows per filter block
#define FTH   256      // filter threads
#define SLOT  2048     // ws key slots per chunk
#define MTH   512      // merge threads
#define NB2   2048     // merge bins (top 11 bits of key)
#define BPT2  4        // NB2 / MTH
#define CBUF  2048
#define RTH   256      // repair threads
#define RNB   4096     // repair bins (top 12 bits of mapped x)
#define RBUF  2048

// Monotone float->uint32 map (order-preserving), exactly invertible.
__device__ __forceinline__ uint32_t fmap(float f) {
    uint32_t u = __float_as_uint(f);
    return (u & 0x80000000u) ? ~u : (u | 0x80000000u);
}
__device__ __forceinline__ float funmap(uint32_t m) {
    uint32_t u = (m & 0x80000000u) ? (m & 0x7fffffffu) : ~m;
    return __uint_as_float(u);
}

// Acklam inverse normal CDF (float). Only needs ~1e-3 accuracy here.
__device__ __forceinline__ float norm_icdf(float p) {
    const float a1=-3.969683028665376e+01f,a2= 2.209460984245205e+02f,a3=-2.759285104469687e+02f,
                a4= 1.383577518672690e+02f,a5=-3.066479806614716e+01f,a6= 2.506628277459239e+00f;
    const float b1=-5.447609879822406e+01f,b2= 1.615858368580409e+02f,b3=-1.556989798598866e+02f,
                b4= 6.680131188771972e+01f,b5=-1.328068155288572e+01f;
    const float c1=-7.784894002430293e-03f,c2=-3.223964580411365e-01f,c3=-2.400758277161838e+00f,
                c4=-2.549732539343734e+00f,c5= 4.374664141464968e+00f,c6= 2.938163982698783e+00f;
    const float d1= 7.784695709041462e-03f,d2= 3.224671290700398e-01f,d3= 2.445134137142996e+00f,
                d4= 3.754408661907416e+00f;
    if (p < 0.02425f) {
        float q = sqrtf(-2.0f * logf(p));
        return (((((c1*q+c2)*q+c3)*q+c4)*q+c5)*q+c6) / ((((d1*q+d2)*q+d3)*q+d4)*q+1.0f);
    } else if (p <= 0.97575f) {
        float q = p - 0.5f, r = q*q;
        return (((((a1*r+a2)*r+a3)*r+a4)*r+a5)*r+a6)*q / (((((b1*r+b2)*r+b3)*r+b4)*r+b5)*r+1.0f);
    } else {
        float q = sqrtf(-2.0f * logf(1.0f - p));
        return -(((((c1*q+c2)*q+c3)*q+c4)*q+c5)*q+c6) / ((((d1*q+d2)*q+d3)*q+d4)*q+1.0f);
    }
}

// Kernel 1: single filtered streaming pass. Keep rows with x <= tau(L).
__global__ __launch_bounds__(FTH) void filter_kernel(
    const float* __restrict__ corners, const int* __restrict__ lengths,
    u64* __restrict__ ws_keys, uint32_t* __restrict__ ws_counts, int M, int NC)
{
    const int blk = blockIdx.x;
    const int b = blk / NC;
    const int q = blk - b * NC;
    const int tid = threadIdx.x;

    int L = lengths[b];
    if (L < 0) L = 0;
    if (L > M) L = M;
    const int start = q * CHUNK;
    int validq = L - start;
    if (validq < 0) validq = 0;
    if (validq > CHUNK) validq = CHUNK;
    if (validq == 0) { if (tid == 0) ws_counts[blk] = 0; return; }

    // analytic threshold: quantile 1.5*K/L of N(0,1), + tiny bump for approx err
    float tau;
    if (L <= (3 * KOUT) / 2) tau = __int_as_float(0x7f800000);  // +inf: keep all
    else tau = norm_icdf(1.5f * (float)KOUT / (float)L) + 0.01f;

    __shared__ uint32_t shcnt;
    if (tid == 0) shcnt = 0u;
    __syncthreads();

    const float2* cp = (const float2*)corners + (size_t)b * M + start;
    const float4* cp4 = (const float4*)cp;
    u64* myws = ws_keys + (size_t)blk * SLOT;
    const int nv = validq >> 1;

    for (int i = tid; i < nv; i += FTH) {
        float4 v = cp4[i];
        if (v.x <= tau) {
            uint32_t p = atomicAdd(&shcnt, 1u);
            if (p < SLOT) myws[p] = ((u64)fmap(v.x) << 32) | fmap(v.y);
        }
        if (v.z <= tau) {
            uint32_t p = atomicAdd(&shcnt, 1u);
            if (p < SLOT) myws[p] = ((u64)fmap(v.z) << 32) | fmap(v.w);
        }
    }
    if ((validq & 1) && tid == 0) {
        float2 c = cp[validq - 1];
        if (c.x <= tau) {
            uint32_t p = atomicAdd(&shcnt, 1u);
            if (p < SLOT) myws[p] = ((u64)fmap(c.x) << 32) | fmap(c.y);
        }
    }
    __syncthreads();
    if (tid == 0) ws_counts[blk] = shcnt;   // unclamped (overflow detectable)
}

// Kernel 2: per batch: verify candidate set, bin-threshold, exact rank-select.
__global__ __launch_bounds__(MTH) void merge_kernel(
    const int* __restrict__ lengths, const u64* __restrict__ ws_keys,
    const uint32_t* __restrict__ ws_counts, float* __restrict__ out,
    uint32_t* __restrict__ flags, int M, int NC)
{
    const int b = blockIdx.x;
    const int tid = threadIdx.x;
    int L = lengths[b];
    if (L < 0) L = 0;
    if (L > M) L = M;
    const int Kb = (L < KOUT) ? L : KOUT;
    float2* outb = (float2*)(out + (size_t)b * (2 * KOUT));

    for (int j = Kb + tid; j < KOUT; j += MTH)
        outb[j] = make_float2(0.0f, 0.0f);
    if (Kb == 0) { if (tid == 0) flags[b] = 0u; return; }

    __shared__ u64 cbuf[CBUF];
    __shared__ uint32_t hist[NB2];
    __shared__ uint32_t wsum[8];
    __shared__ uint32_t shT, shcnt, shbad;

    for (int i = tid; i < NB2; i += MTH) hist[i] = 0u;
    if (tid == 0) { shT = NB2 - 1; shcnt = 0u; shbad = 0u; }
    __syncthreads();

    const u64* base = ws_keys + (size_t)b * NC * SLOT;
    uint32_t C = 0;
    for (int q = 0; q < NC; ++q) {
        uint32_t cq = ws_counts[b * NC + q];
        if (cq > SLOT) { shbad = 1u; cq = SLOT; }
        C += cq;
        const u64* lst = base + (size_t)q * SLOT;
        for (int i = tid; i < (int)cq; i += MTH)
            atomicAdd(&hist[(uint32_t)(lst[i] >> 53)], 1u);
    }
    __syncthreads();
    if (shbad || C < (uint32_t)Kb) { if (tid == 0) flags[b] = 1u; return; }

    // shuffle-scan of per-thread 4-bin sums; find threshold bin T
    {
        uint32_t s = 0;
        const int basebin = tid * BPT2;
        for (int g = 0; g < BPT2; ++g) s += hist[basebin + g];
        const int lane = tid & 63, wid = tid >> 6;
        uint32_t v = s;
        for (int off = 1; off < 64; off <<= 1) {
            uint32_t t = __shfl_up(v, (unsigned)off, 64);
            if (lane >= off) v += t;
        }
        if (lane == 63) wsum[wid] = v;
        __syncthreads();
        if (tid < 8) {
            uint32_t x = wsum[tid];
            for (int off = 1; off < 8; off <<= 1) {
                uint32_t t = __shfl_up(x, (unsigned)off, 8);
                if (tid >= off) x += t;
            }
            wsum[tid] = x;
        }
        __syncthreads();
        const uint32_t woff = (wid > 0) ? wsum[wid - 1] : 0u;
        const uint32_t incl = v + woff;
        const uint32_t excl = incl - s;
        if ((uint32_t)Kb > excl && (uint32_t)Kb <= incl) {
            uint32_t run = excl;
            int g = 0;
            for (;;) {
                run += hist[basebin + g];
                if (run >= (uint32_t)Kb) break;
                ++g;
            }
            shT = (uint32_t)(basebin + g);
        }
        __syncthreads();
    }
    const uint32_t T = shT;

    for (int q = 0; q < NC; ++q) {
        uint32_t cq = ws_counts[b * NC + q];
        if (cq > SLOT) cq = SLOT;
        const u64* lst = base + (size_t)q * SLOT;
        for (int i = tid; i < (int)cq; i += MTH) {
            u64 key = lst[i];
            if ((uint32_t)(key >> 53) <= T) {
                uint32_t p = atomicAdd(&shcnt, 1u);
                if (p < CBUF) cbuf[p] = key;
            }
        }
    }
    __syncthreads();
    if (shcnt > CBUF) { if (tid == 0) flags[b] = 1u; return; }
    const int n2 = (int)shcnt;

    for (int i = tid; i < n2; i += MTH) {
        u64 ki = cbuf[i];
        uint32_t r = 0;
        for (int j = 0; j < n2; ++j) {
            u64 kj = cbuf[j];
            r += (kj < ki) || (kj == ki && j < i);
        }
        if (r < (uint32_t)Kb)
            outb[r] = make_float2(funmap((uint32_t)(ki >> 32)), funmap((uint32_t)ki));
    }
    if (tid == 0) flags[b] = 0u;
}

// Kernel 3: exact fallback for flagged batches (statistically never runs).
__global__ __launch_bounds__(RTH) void repair_kernel(
    const float* __restrict__ corners, const int* __restrict__ lengths,
    const uint32_t* __restrict__ flags, float* __restrict__ out, int M)
{
    const int b = blockIdx.x;
    if (flags[b] == 0u) return;
    const int tid = threadIdx.x;
    int L = lengths[b];
    if (L < 0) L = 0;
    if (L > M) L = M;
    const int Kb = (L < KOUT) ? L : KOUT;
    if (Kb == 0) return;
    float2* outb = (float2*)(out + (size_t)b * (2 * KOUT));

    __shared__ uint32_t hist[RNB];
    __shared__ u64 cbuf[RBUF];
    __shared__ uint32_t shT, shcnt;
    for (int i = tid; i < RNB; i += RTH) hist[i] = 0u;
    if (tid == 0) { shT = RNB - 1; shcnt = 0u; }
    __syncthreads();

    const float2* cp = (const float2*)corners + (size_t)b * M;
    for (int i = tid; i < L; i += RTH)
        atomicAdd(&hist[fmap(cp[i].x) >> 20], 1u);
    __syncthreads();

    if (tid == 0) {
        uint32_t run = 0;
        for (int g = 0; g < RNB; ++g) {
            run += hist[g];
            if (run >= (uint32_t)Kb) { shT = (uint32_t)g; break; }
        }
    }
    __syncthreads();
    const uint32_t T = shT;

    for (int i = tid; i < L; i += RTH) {
        float2 c = cp[i];
        uint32_t kx = fmap(c.x);
        if ((kx >> 20) <= T) {
            uint32_t p = atomicAdd(&shcnt, 1u);
            if (p < RBUF) cbuf[p] = ((u64)kx << 32) | fmap(c.y);
        }
    }
    __syncthreads();
    int n = (int)((shcnt < RBUF) ? shcnt : RBUF);

    for (int i = tid; i < n; i += RTH) {
        u64 ki = cbuf[i];
        uint32_t r = 0;
        for (int j = 0; j < n; ++j) {
            u64 kj = cbuf[j];
            r += (kj < ki) || (kj == ki && j < i);
        }
        if (r < (uint32_t)Kb)
            outb[r] = make_float2(funmap((uint32_t)(ki >> 32)), funmap((uint32_t)ki));
    }
}

extern "C" void kernel_launch(void* const* d_in, const int* in_sizes, int n_in,
                              void* d_out, int out_size, void* d_ws, size_t ws_size,
                              hipStream_t stream) {
    const float* corners = (const float*)d_in[0];
    const int* lengths   = (const int*)d_in[1];
    float* out = (float*)d_out;
    const int B = in_sizes[1];
    const int M = in_sizes[0] / (B * 2);
    const int NC = (M + CHUNK - 1) / CHUNK;   // 8 for M=32768

    u64* ws_keys = (u64*)d_ws;
    uint32_t* ws_counts = (uint32_t*)((char*)d_ws + (size_t)B * NC * SLOT * sizeof(u64));
    uint32_t* flags = ws_counts + (size_t)B * NC;

    filter_kernel<<<B * NC, FTH, 0, stream>>>(corners, lengths, ws_keys, ws_counts, M, NC);
    merge_kernel<<<B, MTH, 0, stream>>>(lengths, ws_keys, ws_counts, out, flags, M, NC);
    repair_kernel<<<B, RTH, 0, stream>>>(corners, lengths, flags, out, M);
}